// Round 12
// baseline (106.236 us; speedup 1.0000x reference)
//
#include <hip/hip_runtime.h>
#include <hip/hip_bf16.h>

typedef unsigned short u16;
typedef unsigned int u32;
typedef __attribute__((ext_vector_type(8))) short bf16x8;
typedef __attribute__((ext_vector_type(4))) float f32x4;

__device__ __forceinline__ u16 f2bf(float f) {
  return __builtin_bit_cast(u16, __float2bfloat16(f));
}

__device__ __forceinline__ bf16x8 ld_frag16(const u16* p) {
  return __builtin_bit_cast(bf16x8, *reinterpret_cast<const uint4*>(p));
}

__device__ __forceinline__ void gload_lds16(const void* g, void* l) {
  __builtin_amdgcn_global_load_lds((const __attribute__((address_space(1))) void*)g,
                                   (__attribute__((address_space(3))) void*)l, 16, 0, 0);
}

__device__ __forceinline__ void bar_lds() {
  asm volatile("s_waitcnt lgkmcnt(0)" ::: "memory");
  __builtin_amdgcn_sched_barrier(0);
  __builtin_amdgcn_s_barrier();
}

// ---------------------------------------------------------------------------
// Kernel 1: Y[b] = bf16( W @ X[b] )   (unchanged)
// ---------------------------------------------------------------------------
__global__ __launch_bounds__(256, 3) void gemm1(
    const float* __restrict__ x, const float* __restrict__ weight,
    u16* __restrict__ Y)
{
  constexpr int Nn = 1024, K = 256, BK = 32, SB = 40;
  __shared__ __align__(16) u16 As[128 * 32];
  __shared__ __align__(16) u16 Bs[64 * SB];

  const int t = threadIdx.x;
  const int b = blockIdx.z, mt = blockIdx.y, n0 = blockIdx.x * 64;

  const float* Wp = weight + (size_t)mt * 128 * K;
  const float* Xb = x + (size_t)b * K * Nn;

  const int w = t >> 6, l = t & 63;
  const int wm = w >> 1, wn = w & 1;
  const int lr = l & 15, lg = l >> 4;

  const int ar = t >> 1, akc = (t & 1) * 16;
  const int bm = t & 63, bkq = t >> 6;
  const float* Xcol = Xb + n0 + bm;

  f32x4 acc[4][2] = {};

  for (int kt = 0; kt < K / BK; ++kt) {
    const int k0 = kt * BK;

    float4 a4[4];
#pragma unroll
    for (int uu = 0; uu < 4; ++uu)
      a4[uu] = reinterpret_cast<const float4*>(Wp + (size_t)ar * K + k0 + akc)[uu];
    union { uint4 q[2]; u16 s[16]; } ua;
#pragma unroll
    for (int uu = 0; uu < 4; ++uu) {
      ua.s[uu * 4 + 0] = f2bf(a4[uu].x); ua.s[uu * 4 + 1] = f2bf(a4[uu].y);
      ua.s[uu * 4 + 2] = f2bf(a4[uu].z); ua.s[uu * 4 + 3] = f2bf(a4[uu].w);
    }
    {
      const int c0 = akc >> 3;
      const int sw = (ar >> 1) & 3;
      uint4* Aq = reinterpret_cast<uint4*>(As);
      Aq[ar * 4 + ((c0 + 0) ^ sw)] = ua.q[0];
      Aq[ar * 4 + ((c0 + 1) ^ sw)] = ua.q[1];
    }

    float v[8];
#pragma unroll
    for (int j = 0; j < 8; ++j)
      v[j] = Xcol[(size_t)(k0 + bkq * 8 + j) * Nn];
    union { uint4 q; u16 s[8]; } ub;
#pragma unroll
    for (int j = 0; j < 8; ++j) ub.s[j] = f2bf(v[j]);
    reinterpret_cast<uint4*>(Bs)[bm * 5 + bkq] = ub.q;

    __syncthreads();

    bf16x8 af[4], bfr[2];
#pragma unroll
    for (int mi = 0; mi < 4; ++mi) {
      const int rr = wm * 64 + mi * 16 + lr;
      const int cw = lg ^ ((rr >> 1) & 3);
      af[mi] = ld_frag16(As + rr * BK + cw * 8);
    }
#pragma unroll
    for (int ni = 0; ni < 2; ++ni) {
      const int cc = wn * 32 + ni * 16 + lr;
      bfr[ni] = ld_frag16(Bs + cc * SB + lg * 8);
    }
#pragma unroll
    for (int mi = 0; mi < 4; ++mi)
#pragma unroll
      for (int ni = 0; ni < 2; ++ni)
        acc[mi][ni] = __builtin_amdgcn_mfma_f32_16x16x32_bf16(
            af[mi], bfr[ni], acc[mi][ni], 0, 0, 0);

    __syncthreads();
  }

#pragma unroll
  for (int mi = 0; mi < 4; ++mi) {
#pragma unroll
    for (int rr = 0; rr < 4; ++rr) {
      const int row = mt * 128 + wm * 64 + mi * 16 + lg * 4 + rr;
      u16* Yrow = Y + ((size_t)(b * 256 + row)) * Nn + n0;
#pragma unroll
      for (int ni = 0; ni < 2; ++ni) {
        const int col = wn * 32 + ni * 16 + lr;
        Yrow[col] = f2bf(acc[mi][ni][rr]);
      }
    }
  }
}

// ---------------------------------------------------------------------------
// Kernel 2 body, templated ablation of the v9 structure.
// ABL=0 full | 1 noB (B-path stubbed, vmcnt(2) stand-in) | 2 noA (As const)
//       | 3 no-COMPUTE (staging+barriers only, Bs2 asm-sunk).
// ---------------------------------------------------------------------------
template <int ABL>
__device__ __forceinline__ void gemm2_body(
    const float* __restrict__ adj1, const float* __restrict__ adj2,
    const u16* __restrict__ Y, const float* __restrict__ bias,
    float* __restrict__ out)
{
  constexpr int Nn = 1024, BK = 32, NT = Nn / BK;
  constexpr int SB1 = 68;
  constexpr int SB2 = 40;
  __shared__ __align__(16) u16 As[4][128 * 32];
  __shared__ __align__(16) u16 Bb[2][32 * SB1];
  __shared__ __align__(16) u16 Bs2[2][64 * SB2];

  const int t = threadIdx.x;

  const int bid = blockIdx.x;
  const int xcd = bid & 7;
  const int nt  = (bid >> 3) & 15;
  const int pg  = bid >> 7;
  const int p   = pg * 8 + xcd;
  const int b   = p >> 1, h = p & 1;
  const int n0  = nt * 64;

  const float* adj = (h == 0 ? adj1 : adj2) + (size_t)b * Nn * Nn;
  const u16* Yb = Y + ((size_t)(b * 256 + h * 128)) * Nn;

  const int w = t >> 6, l = t & 63;
  const int wm = w >> 1, wn = w & 1;
  const int lr = l & 15, lg = l >> 4;

  const int a_r = t >> 2, a_c = t & 3;
  const int a_cg = a_c ^ ((a_r >> 1) & 3);
  const u16* a_src = Yb + (size_t)a_r * Nn + a_cg * 8;
  const int a_dst0 = (w * 64) * 8;
  const int a_dst1 = (256 + w * 64) * 8;

  const int b1r = t >> 4, b1c4 = t & 15;
  const float* bsrc0 = adj + (size_t)b1r * Nn + n0 + 4 * b1c4;
  const float* bsrc1 = adj + (size_t)(b1r + 16) * Nn + n0 + 4 * b1c4;

  const int p2n = t >> 2, p2kq = t & 3;

  f32x4 acc[4][2] = {};

  auto ISSUE_A = [&](int tt) {
    gload_lds16(a_src + tt * BK, (void*)(&As[tt & 3][0] + a_dst0));
    gload_lds16(a_src + (size_t)64 * Nn + tt * BK, (void*)(&As[tt & 3][0] + a_dst1));
  };
  auto LOAD_B = [&](int tt, float4 (&v)[2]) {
    v[0] = *reinterpret_cast<const float4*>(bsrc0 + (size_t)tt * BK * Nn);
    v[1] = *reinterpret_cast<const float4*>(bsrc1 + (size_t)tt * BK * Nn);
  };
  auto PASS1 = [&](int tt, const float4 (&v)[2]) {
#pragma unroll
    for (int i = 0; i < 2; ++i) {
      union { uint2 q; u16 s[4]; } ub;
      ub.s[0] = f2bf(v[i].x); ub.s[1] = f2bf(v[i].y);
      ub.s[2] = f2bf(v[i].z); ub.s[3] = f2bf(v[i].w);
      *reinterpret_cast<uint2*>(&Bb[tt & 1][0] + (i * 16 + b1r) * SB1 + 4 * b1c4) = ub.q;
    }
  };
  auto PASS2 = [&](int tt) {
    const u16* src = &Bb[tt & 1][0];
    union { uint4 q; u16 s[8]; } up;
#pragma unroll
    for (int j2 = 0; j2 < 8; ++j2)
      up.s[j2] = src[(p2kq * 8 + j2) * SB1 + p2n];
    *reinterpret_cast<uint4*>(&Bs2[tt & 1][0] + p2n * SB2 + p2kq * 8) = up.q;
  };
  auto COMPUTE = [&](int tt) {
    const u16* Ab = &As[tt & 3][0];
    const u16* Bbf = &Bs2[tt & 1][0];
    bf16x8 af[4], bfr[2];
#pragma unroll
    for (int mi = 0; mi < 4; ++mi) {
      const int rr = wm * 64 + mi * 16 + lr;
      const int cw = lg ^ ((rr >> 1) & 3);
      af[mi] = ld_frag16(Ab + rr * BK + cw * 8);
    }
#pragma unroll
    for (int ni = 0; ni < 2; ++ni) {
      const int cc = wn * 32 + ni * 16 + lr;
      bfr[ni] = ld_frag16(Bbf + cc * SB2 + lg * 8);
    }
#pragma unroll
    for (int mi = 0; mi < 4; ++mi)
#pragma unroll
      for (int ni = 0; ni < 2; ++ni)
        acc[mi][ni] = __builtin_amdgcn_mfma_f32_16x16x32_bf16(
            af[mi], bfr[ni], acc[mi][ni], 0, 0, 0);
  };

  // ---- stub inits ----
  if constexpr (ABL == 1) {   // noB: constant Bs2 (2*64*40 u16 = 640 uint4)
    for (int i = t; i < 640; i += 256)
      reinterpret_cast<uint4*>(&Bs2[0][0])[i] =
          make_uint4(0x3F803F80u, 0x3F803F80u, 0x3F803F80u, 0x3F803F80u);
  }
  if constexpr (ABL == 2) {   // noA: constant As (4*128*32 u16 = 2048 uint4)
    for (int i = t; i < 2048; i += 256)
      reinterpret_cast<uint4*>(&As[0][0])[i] =
          make_uint4(0x3F803F80u, 0x3F803F80u, 0x3F803F80u, 0x3F803F80u);
  }
  if constexpr (ABL == 1 || ABL == 2) __syncthreads();

  float4 regA[2], regB[2];

  // ---- prologue ----
  if constexpr (ABL != 2) { ISSUE_A(0); ISSUE_A(1); }
  if constexpr (ABL != 1) { LOAD_B(0, regA); LOAD_B(1, regB); }
  if constexpr (ABL == 1) {
    asm volatile("s_waitcnt vmcnt(2)" ::: "memory");
  } else {
    PASS1(0, regA);
  }
  bar_lds();

  // ---- main loop ----
  for (int jj = 0; jj < NT / 2; ++jj) {
    const int j0 = 2 * jj;
    if (j0 + 2 < NT) {
      if constexpr (ABL != 2) ISSUE_A(j0 + 2);
      if constexpr (ABL != 1) LOAD_B(j0 + 2, regA);
    }
    if constexpr (ABL == 1) {
      asm volatile("s_waitcnt vmcnt(2)" ::: "memory");
    } else {
      PASS1(j0 + 1, regB);
    }
    if constexpr (ABL != 1) PASS2(j0);
    bar_lds();
    if constexpr (ABL != 3) COMPUTE(j0);

    const int j1 = j0 + 1;
    if (j1 + 2 < NT) {
      if constexpr (ABL != 2) ISSUE_A(j1 + 2);
      if constexpr (ABL != 1) LOAD_B(j1 + 2, regB);
    }
    if constexpr (ABL == 1) {
      asm volatile("s_waitcnt vmcnt(2)" ::: "memory");
    } else {
      if (j1 + 1 < NT) PASS1(j1 + 1, regA);
    }
    if constexpr (ABL != 1) PASS2(j1);
    bar_lds();
    if constexpr (ABL != 3) COMPUTE(j1);
  }

  if constexpr (ABL == 3) {   // keep Bs2 writes live (rule #17)
    u16 sink = Bs2[0][t] + Bs2[1][t] + As[0][t];
    asm volatile("" :: "v"((u32)sink));
  }

  // ---- epilogue ----
#pragma unroll
  for (int mi = 0; mi < 4; ++mi) {
#pragma unroll
    for (int rr = 0; rr < 4; ++rr) {
      const int go = h * 128 + wm * 64 + mi * 16 + lg * 4 + rr;
      const float bi = bias[go];
      float* orow = out + ((size_t)(b * 256 + go)) * Nn + n0;
#pragma unroll
      for (int ni = 0; ni < 2; ++ni) {
        const int col = wn * 32 + ni * 16 + lr;
        orow[col] = fmaxf(acc[mi][ni][rr] + bi, 0.f);
      }
    }
  }
}

__global__ __launch_bounds__(256, 2) void ab_noB(
    const float* __restrict__ a1, const float* __restrict__ a2,
    const u16* __restrict__ Y, const float* __restrict__ bi, float* __restrict__ o)
{ gemm2_body<1>(a1, a2, Y, bi, o); }

__global__ __launch_bounds__(256, 2) void ab_noA(
    const float* __restrict__ a1, const float* __restrict__ a2,
    const u16* __restrict__ Y, const float* __restrict__ bi, float* __restrict__ o)
{ gemm2_body<2>(a1, a2, Y, bi, o); }

__global__ __launch_bounds__(256, 2) void ab_stage(
    const float* __restrict__ a1, const float* __restrict__ a2,
    const u16* __restrict__ Y, const float* __restrict__ bi, float* __restrict__ o)
{ gemm2_body<3>(a1, a2, Y, bi, o); }

__global__ __launch_bounds__(256, 2) void gemm2_full(
    const float* __restrict__ a1, const float* __restrict__ a2,
    const u16* __restrict__ Y, const float* __restrict__ bi, float* __restrict__ o)
{ gemm2_body<0>(a1, a2, Y, bi, o); }

extern "C" void kernel_launch(void* const* d_in, const int* in_sizes, int n_in,
                              void* d_out, int out_size, void* d_ws, size_t ws_size,
                              hipStream_t stream) {
  const float* x    = (const float*)d_in[0];
  const float* adj1 = (const float*)d_in[1];
  const float* adj2 = (const float*)d_in[2];
  const float* wgt  = (const float*)d_in[3];
  const float* bias = (const float*)d_in[4];
  float* out = (float*)d_out;
  u16* Y = (u16*)d_ws;

  dim3 g1(16, 2, 16);
  gemm1<<<g1, dim3(256), 0, stream>>>(x, wgt, Y);

  // Ablation probes (outputs overwritten by gemm2_full below).
  ab_noB  <<<dim3(512), dim3(256), 0, stream>>>(adj1, adj2, Y, bias, out);
  ab_noA  <<<dim3(512), dim3(256), 0, stream>>>(adj1, adj2, Y, bias, out);
  ab_stage<<<dim3(512), dim3(256), 0, stream>>>(adj1, adj2, Y, bias, out);

  // The real kernel, last: final d_out is correct.
  gemm2_full<<<dim3(512), dim3(256), 0, stream>>>(adj1, adj2, Y, bias, out);
}

// Round 14
// 49.043 us; speedup vs baseline: 2.1662x; 2.1662x over previous
//
#include <hip/hip_runtime.h>
#include <hip/hip_bf16.h>

typedef unsigned short u16;
typedef unsigned int u32;
typedef __attribute__((ext_vector_type(8))) short bf16x8;
typedef __attribute__((ext_vector_type(4))) float f32x4;

__device__ __forceinline__ u16 f2bf(float f) {
  return __builtin_bit_cast(u16, __float2bfloat16(f));
}

__device__ __forceinline__ bf16x8 ld_frag16(const u16* p) {
  return __builtin_bit_cast(bf16x8, *reinterpret_cast<const uint4*>(p));
}

__device__ __forceinline__ void gload_lds16(const void* g, void* l) {
  __builtin_amdgcn_global_load_lds((const __attribute__((address_space(1))) void*)g,
                                   (__attribute__((address_space(3))) void*)l, 16, 0, 0);
}

// Barrier without vmcnt drain: publish LDS writes, fence scheduler, raw barrier.
__device__ __forceinline__ void bar_lds() {
  asm volatile("s_waitcnt lgkmcnt(0)" ::: "memory");
  __builtin_amdgcn_sched_barrier(0);
  __builtin_amdgcn_s_barrier();
}

// ---------------------------------------------------------------------------
// Kernel 1: Y[b] = bf16( W @ X[b] )   (unchanged)
// ---------------------------------------------------------------------------
__global__ __launch_bounds__(256, 3) void gemm1(
    const float* __restrict__ x, const float* __restrict__ weight,
    u16* __restrict__ Y)
{
  constexpr int Nn = 1024, K = 256, BK = 32, SB = 40;
  __shared__ __align__(16) u16 As[128 * 32];
  __shared__ __align__(16) u16 Bs[64 * SB];

  const int t = threadIdx.x;
  const int b = blockIdx.z, mt = blockIdx.y, n0 = blockIdx.x * 64;

  const float* Wp = weight + (size_t)mt * 128 * K;
  const float* Xb = x + (size_t)b * K * Nn;

  const int w = t >> 6, l = t & 63;
  const int wm = w >> 1, wn = w & 1;
  const int lr = l & 15, lg = l >> 4;

  const int ar = t >> 1, akc = (t & 1) * 16;
  const int bm = t & 63, bkq = t >> 6;
  const float* Xcol = Xb + n0 + bm;

  f32x4 acc[4][2] = {};

  for (int kt = 0; kt < K / BK; ++kt) {
    const int k0 = kt * BK;

    float4 a4[4];
#pragma unroll
    for (int uu = 0; uu < 4; ++uu)
      a4[uu] = reinterpret_cast<const float4*>(Wp + (size_t)ar * K + k0 + akc)[uu];
    union { uint4 q[2]; u16 s[16]; } ua;
#pragma unroll
    for (int uu = 0; uu < 4; ++uu) {
      ua.s[uu * 4 + 0] = f2bf(a4[uu].x); ua.s[uu * 4 + 1] = f2bf(a4[uu].y);
      ua.s[uu * 4 + 2] = f2bf(a4[uu].z); ua.s[uu * 4 + 3] = f2bf(a4[uu].w);
    }
    {
      const int c0 = akc >> 3;
      const int sw = (ar >> 1) & 3;
      uint4* Aq = reinterpret_cast<uint4*>(As);
      Aq[ar * 4 + ((c0 + 0) ^ sw)] = ua.q[0];
      Aq[ar * 4 + ((c0 + 1) ^ sw)] = ua.q[1];
    }

    float v[8];
#pragma unroll
    for (int j = 0; j < 8; ++j)
      v[j] = Xcol[(size_t)(k0 + bkq * 8 + j) * Nn];
    union { uint4 q; u16 s[8]; } ub;
#pragma unroll
    for (int j = 0; j < 8; ++j) ub.s[j] = f2bf(v[j]);
    reinterpret_cast<uint4*>(Bs)[bm * 5 + bkq] = ub.q;

    __syncthreads();

    bf16x8 af[4], bfr[2];
#pragma unroll
    for (int mi = 0; mi < 4; ++mi) {
      const int rr = wm * 64 + mi * 16 + lr;
      const int cw = lg ^ ((rr >> 1) & 3);
      af[mi] = ld_frag16(As + rr * BK + cw * 8);
    }
#pragma unroll
    for (int ni = 0; ni < 2; ++ni) {
      const int cc = wn * 32 + ni * 16 + lr;
      bfr[ni] = ld_frag16(Bs + cc * SB + lg * 8);
    }
#pragma unroll
    for (int mi = 0; mi < 4; ++mi)
#pragma unroll
      for (int ni = 0; ni < 2; ++ni)
        acc[mi][ni] = __builtin_amdgcn_mfma_f32_16x16x32_bf16(
            af[mi], bfr[ni], acc[mi][ni], 0, 0, 0);

    __syncthreads();
  }

#pragma unroll
  for (int mi = 0; mi < 4; ++mi) {
#pragma unroll
    for (int rr = 0; rr < 4; ++rr) {
      const int row = mt * 128 + wm * 64 + mi * 16 + lg * 4 + rr;
      u16* Yrow = Y + ((size_t)(b * 256 + row)) * Nn + n0;
#pragma unroll
      for (int ni = 0; ni < 2; ++ni) {
        const int col = wn * 32 + ni * 16 + lr;
        Yrow[col] = f2bf(acc[mi][ni][rr]);
      }
    }
  }
}

// ---------------------------------------------------------------------------
// Kernel 2 (v11): out = relu(Y_slab @ adj_h + bias)
// BM=64, BN=256, BK=32. Grid 256 = 32 (b,h) pairs x 2 m-halves x 4 n-tiles,
// XCD-clustered: all 8 blocks of a pair share one XCD; the 4 n-tiles
// cooperatively cover full 4KB adj rows (1KB contiguous per wave-instr —
// v4's best-measured pattern), the mh pair merges in L2.
// 512 thr, 8 waves (2m x 4n, wave tile 32x64). v6 pipeline: dist-2 globals,
// 4-buffer A ring, dbuf Bb/Bs2 two-pass transpose, 1 lgkm-barrier/tile.
// ---------------------------------------------------------------------------
__global__ __launch_bounds__(512, 1) void gemm2(
    const float* __restrict__ adj1, const float* __restrict__ adj2,
    const u16* __restrict__ Y, const float* __restrict__ bias,
    float* __restrict__ out)
{
  constexpr int Nn = 1024, BK = 32, NT = Nn / BK;
  constexpr int SB1 = 264;   // Bb row stride (elems): 256 + 8 pad
  constexpr int SB2 = 40;    // Bs2 col stride (elems): 32 + 8 pad
  __shared__ __align__(16) u16 As[4][64 * 32];     // 4 x 4 KB
  __shared__ __align__(16) u16 Bb[2][32 * SB1];    // 2 x 16.5 KB [k][n] bf16
  __shared__ __align__(16) u16 Bs2[2][256 * SB2];  // 2 x 20 KB   [n][k] bf16

  const int t = threadIdx.x;

  // Cluster decode: bid = xcd + 8*(mh + 2*nt) + 64*pg ; pair p = pg*8+xcd.
  const int bid = blockIdx.x;
  const int xcd = bid & 7;
  const int i8  = (bid >> 3) & 7;
  const int mh  = i8 & 1, nt = i8 >> 1;      // 2 m-halves, 4 n-tiles
  const int pg  = bid >> 6;
  const int p   = pg * 8 + xcd;              // 0..31
  const int b   = p >> 1, h = p & 1;
  const int n0  = nt * 256;

  const float* adj = (h == 0 ? adj1 : adj2) + (size_t)b * Nn * Nn;
  const u16* Yb = Y + ((size_t)(b * 256 + h * 128 + mh * 64)) * Nn;  // [64][1024]

  const int w = t >> 6, l = t & 63;
  const int wm = w >> 2, wn = w & 3;          // 2 m x 4 n waves
  const int lr = l & 15, lg = l >> 4;

  // ---- A staging: 256 chunks of 16B (64 rows x 4), waves 0-3 (t<256) ----
  const int a_r = t >> 2, a_c = t & 3;
  const int a_cg = a_c ^ ((a_r >> 1) & 3);
  const u16* a_src = Yb + (size_t)a_r * Nn + a_cg * 8;   // + tt*BK at use
  const int a_dstoff = (w * 64) * 8;                      // u16 elems (w<4)

  // ---- B pass2: thread owns col c = t>>1 (0..255), k-half = t&1 ----
  const int p2c = t >> 1, p2kh = t & 1;

  f32x4 acc[2][4] = {};

  auto ISSUE_A = [&](int tt) {
    if (t < 256)
      gload_lds16(a_src + tt * BK, (void*)(&As[tt & 3][0] + a_dstoff));
  };
  // tile = 32 rows x 256 cols = 2048 float4; thread t: f4 #(t + 512i), i=0..3
  auto LOAD_B = [&](int tt, float4 (&v)[4]) {
#pragma unroll
    for (int i = 0; i < 4; ++i) {
      const int ch = t + 512 * i;
      const int r = ch >> 6, cq = ch & 63;
      v[i] = *reinterpret_cast<const float4*>(
          adj + (size_t)(tt * BK + r) * Nn + n0 + 4 * cq);
    }
  };
  auto PASS1 = [&](int tt, const float4 (&v)[4]) {
    u16* dst = &Bb[tt & 1][0];
#pragma unroll
    for (int i = 0; i < 4; ++i) {
      const int ch = t + 512 * i;
      const int r = ch >> 6, cq = ch & 63;
      union { uint2 q; u16 e[4]; } ub;
      ub.e[0] = f2bf(v[i].x); ub.e[1] = f2bf(v[i].y);
      ub.e[2] = f2bf(v[i].z); ub.e[3] = f2bf(v[i].w);
      *reinterpret_cast<uint2*>(dst + r * SB1 + 4 * cq) = ub.q;
    }
  };
  auto PASS2 = [&](int tt) {
    const u16* src = &Bb[tt & 1][0];
    union { uint4 q[2]; u16 e[16]; } up;
#pragma unroll
    for (int j = 0; j < 16; ++j)
      up.e[j] = src[(p2kh * 16 + j) * SB1 + p2c];
    uint4* dst = reinterpret_cast<uint4*>(&Bs2[tt & 1][0] + p2c * SB2 + p2kh * 16);
    dst[0] = up.q[0];
    dst[1] = up.q[1];
  };
  auto COMPUTE = [&](int tt) {
    const u16* Ab = &As[tt & 3][0];
    const u16* Bbf = &Bs2[tt & 1][0];
    bf16x8 af[2], bfr[4];
#pragma unroll
    for (int mi = 0; mi < 2; ++mi) {
      const int rr = wm * 32 + mi * 16 + lr;
      const int cw = lg ^ ((rr >> 1) & 3);
      af[mi] = ld_frag16(Ab + rr * BK + cw * 8);
    }
#pragma unroll
    for (int ni = 0; ni < 4; ++ni) {
      const int cc = wn * 64 + ni * 16 + lr;
      bfr[ni] = ld_frag16(Bbf + cc * SB2 + lg * 8);
    }
#pragma unroll
    for (int mi = 0; mi < 2; ++mi)
#pragma unroll
      for (int ni = 0; ni < 4; ++ni)
        acc[mi][ni] = __builtin_amdgcn_mfma_f32_16x16x32_bf16(
            af[mi], bfr[ni], acc[mi][ni], 0, 0, 0);
  };

  float4 regA[4], regB[4];   // even tiles -> regA, odd -> regB (static sets)

  // ---- prologue: tiles 0,1 issued; Bb[0] published ----
  ISSUE_A(0); LOAD_B(0, regA);
  ISSUE_A(1); LOAD_B(1, regB);
  PASS1(0, regA);            // vmcnt wait on regA also proves As[0] landed
  bar_lds();

  // ---- main loop (NT=32), unrolled x2 for static regA/regB ping-pong ----
  for (int jj = 0; jj < NT / 2; ++jj) {
    const int j0 = 2 * jj;
    if (j0 + 2 < NT) { ISSUE_A(j0 + 2); LOAD_B(j0 + 2, regA); }
    PASS1(j0 + 1, regB);     // counted vmcnt: newer ops stay in flight
    PASS2(j0);
    bar_lds();
    COMPUTE(j0);

    const int j1 = j0 + 1;
    if (j1 + 2 < NT) { ISSUE_A(j1 + 2); LOAD_B(j1 + 2, regB); }
    if (j1 + 1 < NT) PASS1(j1 + 1, regA);
    PASS2(j1);
    bar_lds();
    COMPUTE(j1);
  }

  // ---- epilogue: bias + relu, fp32 store ----
#pragma unroll
  for (int mi = 0; mi < 2; ++mi) {
#pragma unroll
    for (int rr = 0; rr < 4; ++rr) {
      const int go = h * 128 + mh * 64 + wm * 32 + mi * 16 + lg * 4 + rr;
      const float bi = bias[go];
      float* orow = out + ((size_t)(b * 256 + go)) * Nn + n0;
#pragma unroll
      for (int ni = 0; ni < 4; ++ni) {
        const int col = wn * 64 + ni * 16 + lr;
        orow[col] = fmaxf(acc[mi][ni][rr] + bi, 0.f);
      }
    }
  }
}

extern "C" void kernel_launch(void* const* d_in, const int* in_sizes, int n_in,
                              void* d_out, int out_size, void* d_ws, size_t ws_size,
                              hipStream_t stream) {
  const float* x    = (const float*)d_in[0];
  const float* adj1 = (const float*)d_in[1];
  const float* adj2 = (const float*)d_in[2];
  const float* wgt  = (const float*)d_in[3];
  const float* bias = (const float*)d_in[4];
  float* out = (float*)d_out;
  u16* Y = (u16*)d_ws;   // 16*256*1024 bf16 = 8.4 MB

  dim3 g1(16, 2, 16);
  gemm1<<<g1, dim3(256), 0, stream>>>(x, wgt, Y);
  gemm2<<<dim3(256), dim3(512), 0, stream>>>(adj1, adj2, Y, bias, out);
}

// Round 17
// 47.827 us; speedup vs baseline: 2.2213x; 1.0254x over previous
//
#include <hip/hip_runtime.h>
#include <hip/hip_bf16.h>

typedef unsigned short u16;
typedef unsigned int u32;
typedef __attribute__((ext_vector_type(8))) short bf16x8;
typedef __attribute__((ext_vector_type(4))) float f32x4;

__device__ __forceinline__ u16 f2bf(float f) {
  return __builtin_bit_cast(u16, __float2bfloat16(f));
}

__device__ __forceinline__ bf16x8 ld_frag16(const u16* p) {
  return __builtin_bit_cast(bf16x8, *reinterpret_cast<const uint4*>(p));
}

__device__ __forceinline__ void gload_lds16(const void* g, void* l) {
  __builtin_amdgcn_global_load_lds((const __attribute__((address_space(1))) void*)g,
                                   (__attribute__((address_space(3))) void*)l, 16, 0, 0);
}

// Barrier without vmcnt drain: publish LDS writes, fence scheduler, raw barrier.
__device__ __forceinline__ void bar_lds() {
  asm volatile("s_waitcnt lgkmcnt(0)" ::: "memory");
  __builtin_amdgcn_sched_barrier(0);
  __builtin_amdgcn_s_barrier();
}

// ---------------------------------------------------------------------------
// Kernel 1: Y[b] = bf16( W @ X[b] )   (unchanged)
// ---------------------------------------------------------------------------
__global__ __launch_bounds__(256, 3) void gemm1(
    const float* __restrict__ x, const float* __restrict__ weight,
    u16* __restrict__ Y)
{
  constexpr int Nn = 1024, K = 256, BK = 32, SB = 40;
  __shared__ __align__(16) u16 As[128 * 32];
  __shared__ __align__(16) u16 Bs[64 * SB];

  const int t = threadIdx.x;
  const int b = blockIdx.z, mt = blockIdx.y, n0 = blockIdx.x * 64;

  const float* Wp = weight + (size_t)mt * 128 * K;
  const float* Xb = x + (size_t)b * K * Nn;

  const int w = t >> 6, l = t & 63;
  const int wm = w >> 1, wn = w & 1;
  const int lr = l & 15, lg = l >> 4;

  const int ar = t >> 1, akc = (t & 1) * 16;
  const int bm = t & 63, bkq = t >> 6;
  const float* Xcol = Xb + n0 + bm;

  f32x4 acc[4][2] = {};

  for (int kt = 0; kt < K / BK; ++kt) {
    const int k0 = kt * BK;

    float4 a4[4];
#pragma unroll
    for (int uu = 0; uu < 4; ++uu)
      a4[uu] = reinterpret_cast<const float4*>(Wp + (size_t)ar * K + k0 + akc)[uu];
    union { uint4 q[2]; u16 s[16]; } ua;
#pragma unroll
    for (int uu = 0; uu < 4; ++uu) {
      ua.s[uu * 4 + 0] = f2bf(a4[uu].x); ua.s[uu * 4 + 1] = f2bf(a4[uu].y);
      ua.s[uu * 4 + 2] = f2bf(a4[uu].z); ua.s[uu * 4 + 3] = f2bf(a4[uu].w);
    }
    {
      const int c0 = akc >> 3;
      const int sw = (ar >> 1) & 3;
      uint4* Aq = reinterpret_cast<uint4*>(As);
      Aq[ar * 4 + ((c0 + 0) ^ sw)] = ua.q[0];
      Aq[ar * 4 + ((c0 + 1) ^ sw)] = ua.q[1];
    }

    float v[8];
#pragma unroll
    for (int j = 0; j < 8; ++j)
      v[j] = Xcol[(size_t)(k0 + bkq * 8 + j) * Nn];
    union { uint4 q; u16 s[8]; } ub;
#pragma unroll
    for (int j = 0; j < 8; ++j) ub.s[j] = f2bf(v[j]);
    reinterpret_cast<uint4*>(Bs)[bm * 5 + bkq] = ub.q;

    __syncthreads();

    bf16x8 af[4], bfr[2];
#pragma unroll
    for (int mi = 0; mi < 4; ++mi) {
      const int rr = wm * 64 + mi * 16 + lr;
      const int cw = lg ^ ((rr >> 1) & 3);
      af[mi] = ld_frag16(As + rr * BK + cw * 8);
    }
#pragma unroll
    for (int ni = 0; ni < 2; ++ni) {
      const int cc = wn * 32 + ni * 16 + lr;
      bfr[ni] = ld_frag16(Bs + cc * SB + lg * 8);
    }
#pragma unroll
    for (int mi = 0; mi < 4; ++mi)
#pragma unroll
      for (int ni = 0; ni < 2; ++ni)
        acc[mi][ni] = __builtin_amdgcn_mfma_f32_16x16x32_bf16(
            af[mi], bfr[ni], acc[mi][ni], 0, 0, 0);

    __syncthreads();
  }

#pragma unroll
  for (int mi = 0; mi < 4; ++mi) {
#pragma unroll
    for (int rr = 0; rr < 4; ++rr) {
      const int row = mt * 128 + wm * 64 + mi * 16 + lg * 4 + rr;
      u16* Yrow = Y + ((size_t)(b * 256 + row)) * Nn + n0;
#pragma unroll
      for (int ni = 0; ni < 2; ++ni) {
        const int col = wn * 32 + ni * 16 + lr;
        Yrow[col] = f2bf(acc[mi][ni][rr]);
      }
    }
  }
}

// ---------------------------------------------------------------------------
// Kernel 2 (v13 = v12 with As ring = 4): out = relu(Y_half @ adj_h + bias)
// BM=128, BN=128, BK=64, NT=16 -> half the barrier phases of v6.
// 256 blocks (XCD pair-clustered), 512 thr (8 waves, 2m x 4n).
// As: 4-BUFFER ring, dist-2. Live set incl. post-barrier laggard COMPUTE:
// {tt-1, tt, tt+1, tt+2} distinct mod 4 (v12's ring-3 violated this:
// (tt+2) == (tt-1) mod 3 -> race; same as the v7 bug).
// 8-chunk XOR swizzle c^(r&7). Bb/Bs2 dbuf two-pass transpose. dist-2
// globals, counted vmcnt, 1 lgkm-barrier/tile; tail tile vmcnt(0).
// LDS: 4*16 + 33 + 36 = 133 KB (1 block/CU).
// ---------------------------------------------------------------------------
__global__ __launch_bounds__(512, 1) void gemm2(
    const float* __restrict__ adj1, const float* __restrict__ adj2,
    const u16* __restrict__ Y, const float* __restrict__ bias,
    float* __restrict__ out)
{
  constexpr int Nn = 1024, BK = 64, NT = Nn / BK;
  constexpr int SB1 = 132;   // Bb row stride (elems): 128 + 4 pad
  constexpr int SB2 = 72;    // Bs2 row stride (elems): 64 + 8 pad
  __shared__ __align__(16) u16 As[4][128 * 64];    // 4 x 16 KB
  __shared__ __align__(16) u16 Bb[2][64 * SB1];    // 2 x 16.5 KB [k][n] bf16
  __shared__ __align__(16) u16 Bs2[2][128 * SB2];  // 2 x 18 KB   [n][k] bf16

  const int t = threadIdx.x;

  // XCD-clustered decode: pair p's 8 n-tile blocks all share bid%8.
  const int bid = blockIdx.x;
  const int xcd = bid & 7;
  const int nt  = (bid >> 3) & 7;
  const int pg  = bid >> 6;
  const int p   = pg * 8 + xcd;    // 0..31
  const int b   = p >> 1, h = p & 1;
  const int n0  = nt * 128;

  const float* adj = (h == 0 ? adj1 : adj2) + (size_t)b * Nn * Nn;
  const u16* Yb = Y + ((size_t)(b * 256 + h * 128)) * Nn;  // [128][1024] bf16

  const int w = t >> 6, l = t & 63;
  const int wm = w >> 2, wn = w & 3;          // 2 m x 4 n waves
  const int lr = l & 15, lg = l >> 4;

  // ---- A staging: 1024 chunks of 16B (128 rows x 8); thread does chunks
  // t and t+512 (row +64, same swizzle since 64%8==0). Source pre-swizzled:
  // chunk (r,c) holds source col-group c^(r&7).
  const int a_r = t >> 3, a_c = t & 7;
  const int a_cg = a_c ^ (a_r & 7);
  const u16* a_src = Yb + (size_t)a_r * Nn + a_cg * 8;    // + tt*BK at use
  const int a_dst0 = (w * 64) * 8;                         // elems
  const int a_dst1 = (512 + w * 64) * 8;

  // ---- B pass1: rows b1r+16i (i=0..3), col chunk 4*(t&31) ----
  const int b1r = t >> 5, b1c = t & 31;      // b1r in [0,16)

  // ---- B pass2: thread owns col n = t>>2 (0..127), k-16th kq = t&3 ----
  const int p2n = t >> 2, p2kq = t & 3;

  f32x4 acc[4][2] = {};

  auto ISSUE_A = [&](int tt) {
    u16* dst = &As[tt & 3][0];
    gload_lds16(a_src + tt * BK, (void*)(dst + a_dst0));
    gload_lds16(a_src + (size_t)64 * Nn + tt * BK, (void*)(dst + a_dst1));
  };
  auto LOAD_B = [&](int tt, float4 (&v)[4]) {
#pragma unroll
    for (int i = 0; i < 4; ++i)
      v[i] = *reinterpret_cast<const float4*>(
          adj + (size_t)(tt * BK + b1r + 16 * i) * Nn + n0 + 4 * b1c);
  };
  auto PASS1 = [&](int tt, const float4 (&v)[4]) {
    u16* dst = &Bb[tt & 1][0];
#pragma unroll
    for (int i = 0; i < 4; ++i) {
      union { uint2 q; u16 e[4]; } ub;
      ub.e[0] = f2bf(v[i].x); ub.e[1] = f2bf(v[i].y);
      ub.e[2] = f2bf(v[i].z); ub.e[3] = f2bf(v[i].w);
      *reinterpret_cast<uint2*>(dst + (b1r + 16 * i) * SB1 + 4 * b1c) = ub.q;
    }
  };
  auto PASS2 = [&](int tt) {
    const u16* src = &Bb[tt & 1][0];
    union { uint4 q[2]; u16 e[16]; } up;
#pragma unroll
    for (int j = 0; j < 16; ++j)
      up.e[j] = src[(p2kq * 16 + j) * SB1 + p2n];
    uint4* dst = reinterpret_cast<uint4*>(&Bs2[tt & 1][0] + p2n * SB2 + p2kq * 16);
    dst[0] = up.q[0];
    dst[1] = up.q[1];
  };
  auto COMPUTE = [&](int tt) {
    const u16* Ab = &As[tt & 3][0];
    const u16* Bbf = &Bs2[tt & 1][0];
#pragma unroll
    for (int s = 0; s < 2; ++s) {
      bf16x8 af[4], bfr[2];
#pragma unroll
      for (int mi = 0; mi < 4; ++mi) {
        const int rr = wm * 64 + mi * 16 + lr;
        const int cw = (s * 4 + lg) ^ (rr & 7);
        af[mi] = ld_frag16(Ab + rr * BK + cw * 8);
      }
#pragma unroll
      for (int ni = 0; ni < 2; ++ni) {
        const int cc = wn * 32 + ni * 16 + lr;
        bfr[ni] = ld_frag16(Bbf + cc * SB2 + s * 32 + lg * 8);
      }
#pragma unroll
      for (int mi = 0; mi < 4; ++mi)
#pragma unroll
        for (int ni = 0; ni < 2; ++ni)
          acc[mi][ni] = __builtin_amdgcn_mfma_f32_16x16x32_bf16(
              af[mi], bfr[ni], acc[mi][ni], 0, 0, 0);
    }
  };

  float4 regA[4], regB[4];   // even tiles -> regA, odd -> regB (static sets)

  // ---- prologue: tiles 0,1 issued; Bb[0] published ----
  ISSUE_A(0); LOAD_B(0, regA);
  ISSUE_A(1); LOAD_B(1, regB);
  PASS1(0, regA);            // vmcnt wait on regA also proves As[0] landed
  bar_lds();

  // ---- main loop (NT=16), unrolled x2 for static regA/regB ping-pong ----
  for (int jj = 0; jj < NT / 2; ++jj) {
    const int j0 = 2 * jj;
    if (j0 + 2 < NT) { ISSUE_A(j0 + 2); LOAD_B(j0 + 2, regA); }
    PASS1(j0 + 1, regB);     // counted vmcnt: newer ops stay in flight
    PASS2(j0);
    bar_lds();
    COMPUTE(j0);

    const int j1 = j0 + 1;
    if (j1 + 2 < NT) { ISSUE_A(j1 + 2); LOAD_B(j1 + 2, regB); }
    if (j1 + 1 < NT) {
      PASS1(j1 + 1, regA);
    } else {
      asm volatile("s_waitcnt vmcnt(0)" ::: "memory");  // drain A(NT-1)
    }
    PASS2(j1);
    bar_lds();
    COMPUTE(j1);
  }

  // ---- epilogue: bias + relu, fp32 store ----
#pragma unroll
  for (int mi = 0; mi < 4; ++mi) {
#pragma unroll
    for (int rr = 0; rr < 4; ++rr) {
      const int go = h * 128 + wm * 64 + mi * 16 + lg * 4 + rr;
      const float bi = bias[go];
      float* orow = out + ((size_t)(b * 256 + go)) * Nn + n0;
#pragma unroll
      for (int ni = 0; ni < 2; ++ni) {
        const int col = wn * 32 + ni * 16 + lr;
        orow[col] = fmaxf(acc[mi][ni][rr] + bi, 0.f);
      }
    }
  }
}

extern "C" void kernel_launch(void* const* d_in, const int* in_sizes, int n_in,
                              void* d_out, int out_size, void* d_ws, size_t ws_size,
                              hipStream_t stream) {
  const float* x    = (const float*)d_in[0];
  const float* adj1 = (const float*)d_in[1];
  const float* adj2 = (const float*)d_in[2];
  const float* wgt  = (const float*)d_in[3];
  const float* bias = (const float*)d_in[4];
  float* out = (float*)d_out;
  u16* Y = (u16*)d_ws;   // 16*256*1024 bf16 = 8.4 MB

  dim3 g1(16, 2, 16);
  gemm1<<<g1, dim3(256), 0, stream>>>(x, wgt, Y);
  gemm2<<<dim3(256), dim3(512), 0, stream>>>(adj1, adj2, Y, bias, out);
}

// Round 18
// 43.643 us; speedup vs baseline: 2.4342x; 1.0959x over previous
//
#include <hip/hip_runtime.h>
#include <hip/hip_bf16.h>

typedef unsigned short u16;
typedef unsigned int u32;
typedef __attribute__((ext_vector_type(8))) short bf16x8;
typedef __attribute__((ext_vector_type(4))) float f32x4;

__device__ __forceinline__ u16 f2bf(float f) {
  return __builtin_bit_cast(u16, __float2bfloat16(f));
}

__device__ __forceinline__ bf16x8 ld_frag16(const u16* p) {
  return __builtin_bit_cast(bf16x8, *reinterpret_cast<const uint4*>(p));
}

__device__ __forceinline__ void gload_lds16(const void* g, void* l) {
  __builtin_amdgcn_global_load_lds((const __attribute__((address_space(1))) void*)g,
                                   (__attribute__((address_space(3))) void*)l, 16, 0, 0);
}

// Barrier without vmcnt drain: publish LDS writes, fence scheduler, raw barrier.
__device__ __forceinline__ void bar_lds() {
  asm volatile("s_waitcnt lgkmcnt(0)" ::: "memory");
  __builtin_amdgcn_sched_barrier(0);
  __builtin_amdgcn_s_barrier();
}

// ---------------------------------------------------------------------------
// Kernel 1: Y[b] = bf16( W @ X[b] )   W:[256][256] f32, X:[256][1024] f32
// Y stored bf16 row-major [b][256][1024] in d_ws.
// ---------------------------------------------------------------------------
__global__ __launch_bounds__(256, 3) void gemm1(
    const float* __restrict__ x, const float* __restrict__ weight,
    u16* __restrict__ Y)
{
  constexpr int Nn = 1024, K = 256, BK = 32, SB = 40;
  __shared__ __align__(16) u16 As[128 * 32];
  __shared__ __align__(16) u16 Bs[64 * SB];

  const int t = threadIdx.x;
  const int b = blockIdx.z, mt = blockIdx.y, n0 = blockIdx.x * 64;

  const float* Wp = weight + (size_t)mt * 128 * K;
  const float* Xb = x + (size_t)b * K * Nn;

  const int w = t >> 6, l = t & 63;
  const int wm = w >> 1, wn = w & 1;
  const int lr = l & 15, lg = l >> 4;

  const int ar = t >> 1, akc = (t & 1) * 16;
  const int bm = t & 63, bkq = t >> 6;
  const float* Xcol = Xb + n0 + bm;

  f32x4 acc[4][2] = {};

  for (int kt = 0; kt < K / BK; ++kt) {
    const int k0 = kt * BK;

    float4 a4[4];
#pragma unroll
    for (int uu = 0; uu < 4; ++uu)
      a4[uu] = reinterpret_cast<const float4*>(Wp + (size_t)ar * K + k0 + akc)[uu];
    union { uint4 q[2]; u16 s[16]; } ua;
#pragma unroll
    for (int uu = 0; uu < 4; ++uu) {
      ua.s[uu * 4 + 0] = f2bf(a4[uu].x); ua.s[uu * 4 + 1] = f2bf(a4[uu].y);
      ua.s[uu * 4 + 2] = f2bf(a4[uu].z); ua.s[uu * 4 + 3] = f2bf(a4[uu].w);
    }
    {
      const int c0 = akc >> 3;
      const int sw = (ar >> 1) & 3;
      uint4* Aq = reinterpret_cast<uint4*>(As);
      Aq[ar * 4 + ((c0 + 0) ^ sw)] = ua.q[0];
      Aq[ar * 4 + ((c0 + 1) ^ sw)] = ua.q[1];
    }

    float v[8];
#pragma unroll
    for (int j = 0; j < 8; ++j)
      v[j] = Xcol[(size_t)(k0 + bkq * 8 + j) * Nn];
    union { uint4 q; u16 s[8]; } ub;
#pragma unroll
    for (int j = 0; j < 8; ++j) ub.s[j] = f2bf(v[j]);
    reinterpret_cast<uint4*>(Bs)[bm * 5 + bkq] = ub.q;

    __syncthreads();

    bf16x8 af[4], bfr[2];
#pragma unroll
    for (int mi = 0; mi < 4; ++mi) {
      const int rr = wm * 64 + mi * 16 + lr;
      const int cw = lg ^ ((rr >> 1) & 3);
      af[mi] = ld_frag16(As + rr * BK + cw * 8);
    }
#pragma unroll
    for (int ni = 0; ni < 2; ++ni) {
      const int cc = wn * 32 + ni * 16 + lr;
      bfr[ni] = ld_frag16(Bs + cc * SB + lg * 8);
    }
#pragma unroll
    for (int mi = 0; mi < 4; ++mi)
#pragma unroll
      for (int ni = 0; ni < 2; ++ni)
        acc[mi][ni] = __builtin_amdgcn_mfma_f32_16x16x32_bf16(
            af[mi], bfr[ni], acc[mi][ni], 0, 0, 0);

    __syncthreads();
  }

#pragma unroll
  for (int mi = 0; mi < 4; ++mi) {
#pragma unroll
    for (int rr = 0; rr < 4; ++rr) {
      const int row = mt * 128 + wm * 64 + mi * 16 + lg * 4 + rr;
      u16* Yrow = Y + ((size_t)(b * 256 + row)) * Nn + n0;
#pragma unroll
      for (int ni = 0; ni < 2; ++ni) {
        const int col = wn * 32 + ni * 16 + lr;
        Yrow[col] = f2bf(acc[mi][ni][rr]);
      }
    }
  }
}

// ---------------------------------------------------------------------------
// Kernel 2 (v6 — best measured: 43.66 us total): out = relu(Y_half@adj_h + b)
// BM=128, BN=128, BK=32. 256 blocks, 512 thr (8 waves, 2m x 4n).
// XCD pair-clustering: the 8 n-tile blocks of one (b,h) pair share an XCD
// (bid%8), merging their row-strip demand in that XCD's L2 (FETCH 98->70MB).
// adj staged ROW-WISE (512B contiguous runs), two-pass LDS transpose,
// dist-2 globals, 4-buffer A ring (live {t-1,t,t+1,t+2} distinct mod 4),
// counted vmcnt, 1 lgkm-only barrier per tile.
// ---------------------------------------------------------------------------
__global__ __launch_bounds__(512, 2) void gemm2(
    const float* __restrict__ adj1, const float* __restrict__ adj2,
    const u16* __restrict__ Y, const float* __restrict__ bias,
    float* __restrict__ out)
{
  constexpr int Nn = 1024, BK = 32, NT = Nn / BK;
  constexpr int SB1 = 132;   // Bb row stride (elems): 128 + 4 pad
  constexpr int SB2 = 40;    // Bs2 row stride (elems)
  __shared__ __align__(16) u16 As[4][128 * 32];     // 4 x 8 KB
  __shared__ __align__(16) u16 Bb[2][32 * SB1];     // 2 x 8.25 KB  [k][n] bf16
  __shared__ __align__(16) u16 Bs2[2][128 * SB2];   // 2 x 10 KB    [n][k] bf16

  const int t = threadIdx.x;

  // XCD-clustered decode: pair p's 8 n-tile blocks all share bid%8.
  const int bid = blockIdx.x;
  const int xcd = bid & 7;
  const int nt  = (bid >> 3) & 7;
  const int pg  = bid >> 6;
  const int p   = xcd + pg * 8;    // 0..31
  const int b   = p >> 1, h = p & 1;
  const int n0  = nt * 128;

  const float* adj = (h == 0 ? adj1 : adj2) + (size_t)b * Nn * Nn;
  const u16* Yb = Y + ((size_t)(b * 256 + h * 128)) * Nn;  // [128][1024] bf16

  const int w = t >> 6, l = t & 63;
  const int wm = w >> 2, wn = w & 3;          // 2 m x 4 n waves
  const int lr = l & 15, lg = l >> 4;

  // ---- A staging: chunk t of 512, source-swizzled ----
  const int a_r = t >> 2, a_c = t & 3;
  const int a_cg = a_c ^ ((a_r >> 1) & 3);
  const u16* a_src = Yb + (size_t)a_r * Nn + a_cg * 8;   // + tt*BK at use
  const int a_dstoff = (w * 64) * 8;                      // u16 elements

  // ---- B pass1: row-wise contiguous reads ----
  const int b1r = t >> 5, b1c4 = t & 31;
  const float* bsrc0 = adj + (size_t)(0 * 16 + b1r) * Nn + n0 + 4 * b1c4;
  const float* bsrc1 = adj + (size_t)(1 * 16 + b1r) * Nn + n0 + 4 * b1c4;

  // ---- B pass2: thread owns col n = t>>2, k-quad kq = t&3 ----
  const int p2n = t >> 2, p2kq = t & 3;

  f32x4 acc[4][2] = {};

  auto ISSUE_A = [&](int tt) {
    gload_lds16(a_src + tt * BK, (void*)(&As[tt & 3][0] + a_dstoff));
  };
  auto LOAD_B = [&](int tt, float4 (&v)[2]) {
    v[0] = *reinterpret_cast<const float4*>(bsrc0 + (size_t)tt * BK * Nn);
    v[1] = *reinterpret_cast<const float4*>(bsrc1 + (size_t)tt * BK * Nn);
  };
  auto PASS1 = [&](int tt, const float4 (&v)[2]) {
#pragma unroll
    for (int i = 0; i < 2; ++i) {
      union { uint2 q; u16 s[4]; } ub;
      ub.s[0] = f2bf(v[i].x); ub.s[1] = f2bf(v[i].y);
      ub.s[2] = f2bf(v[i].z); ub.s[3] = f2bf(v[i].w);
      *reinterpret_cast<uint2*>(&Bb[tt & 1][0] + (i * 16 + b1r) * SB1 + 4 * b1c4) = ub.q;
    }
  };
  auto PASS2 = [&](int tt) {
    const u16* src = &Bb[tt & 1][0];
    union { uint4 q; u16 s[8]; } up;
#pragma unroll
    for (int j2 = 0; j2 < 8; ++j2)
      up.s[j2] = src[(p2kq * 8 + j2) * SB1 + p2n];
    *reinterpret_cast<uint4*>(&Bs2[tt & 1][0] + p2n * SB2 + p2kq * 8) = up.q;
  };
  auto COMPUTE = [&](int tt) {
    const u16* Ab = &As[tt & 3][0];
    const u16* Bbf = &Bs2[tt & 1][0];
    bf16x8 af[4], bfr[2];
#pragma unroll
    for (int mi = 0; mi < 4; ++mi) {
      const int rr = wm * 64 + mi * 16 + lr;
      const int cw = lg ^ ((rr >> 1) & 3);
      af[mi] = ld_frag16(Ab + rr * BK + cw * 8);
    }
#pragma unroll
    for (int ni = 0; ni < 2; ++ni) {
      const int cc = wn * 32 + ni * 16 + lr;
      bfr[ni] = ld_frag16(Bbf + cc * SB2 + lg * 8);
    }
#pragma unroll
    for (int mi = 0; mi < 4; ++mi)
#pragma unroll
      for (int ni = 0; ni < 2; ++ni)
        acc[mi][ni] = __builtin_amdgcn_mfma_f32_16x16x32_bf16(
            af[mi], bfr[ni], acc[mi][ni], 0, 0, 0);
  };

  float4 regA[2], regB[2];   // even-tile loads -> regA, odd -> regB

  // ---- prologue: tiles 0,1 issued; Bb[0] published ----
  ISSUE_A(0); LOAD_B(0, regA);
  ISSUE_A(1); LOAD_B(1, regB);
  PASS1(0, regA);            // vmcnt wait on regA also proves As[0] landed
  bar_lds();

  // ---- main loop (NT=32), unrolled x2 for static regA/regB ping-pong ----
  for (int jj = 0; jj < NT / 2; ++jj) {
    const int j0 = 2 * jj;
    if (j0 + 2 < NT) { ISSUE_A(j0 + 2); LOAD_B(j0 + 2, regA); }
    PASS1(j0 + 1, regB);     // counted vmcnt: newer ops stay in flight
    PASS2(j0);
    bar_lds();
    COMPUTE(j0);

    const int j1 = j0 + 1;
    if (j1 + 2 < NT) { ISSUE_A(j1 + 2); LOAD_B(j1 + 2, regB); }
    if (j1 + 1 < NT) PASS1(j1 + 1, regA);
    PASS2(j1);
    bar_lds();
    COMPUTE(j1);
  }

  // ---- epilogue: bias + relu, fp32 store ----
#pragma unroll
  for (int mi = 0; mi < 4; ++mi) {
#pragma unroll
    for (int rr = 0; rr < 4; ++rr) {
      const int go = h * 128 + wm * 64 + mi * 16 + lg * 4 + rr;
      const float bi = bias[go];
      float* orow = out + ((size_t)(b * 256 + go)) * Nn + n0;
#pragma unroll
      for (int ni = 0; ni < 2; ++ni) {
        const int col = wn * 32 + ni * 16 + lr;
        orow[col] = fmaxf(acc[mi][ni][rr] + bi, 0.f);
      }
    }
  }
}

extern "C" void kernel_launch(void* const* d_in, const int* in_sizes, int n_in,
                              void* d_out, int out_size, void* d_ws, size_t ws_size,
                              hipStream_t stream) {
  const float* x    = (const float*)d_in[0];
  const float* adj1 = (const float*)d_in[1];
  const float* adj2 = (const float*)d_in[2];
  const float* wgt  = (const float*)d_in[3];
  const float* bias = (const float*)d_in[4];
  float* out = (float*)d_out;
  u16* Y = (u16*)d_ws;   // 16*256*1024 bf16 = 8.4 MB

  dim3 g1(16, 2, 16);
  gemm1<<<g1, dim3(256), 0, stream>>>(x, wgt, Y);
  gemm2<<<dim3(256), dim3(512), 0, stream>>>(adj1, adj2, Y, bias, out);
}